// Round 6
// baseline (528.949 us; speedup 1.0000x reference)
//
#include <hip/hip_runtime.h>
#include <math.h>

// Problem constants (match reference file).
#define BATCH 256
#define VOCAB 128000
#define HIST  2048
#define EPS_T 1e-5f

// --- barrier-free streaming scan ---
#define BBLOCK 256
#define BLOCKS_PER_ROW 8
#define GRID (BATCH * BLOCKS_PER_ROW)      // 2048 blocks = exactly 8/CU, co-resident
#define WAVES_PER_ROW (BLOCKS_PER_ROW * 4) // 32 autonomous waves per row
#define CHUNKS (VOCAB / 256)               // 500 chunks of 256 elems per row
#define MASK_WORDS (VOCAB / 32)            // 4000 words = 16 KB full-row mask

typedef float f32x4 __attribute__((ext_vector_type(4)));

// Order-preserving f32 -> u32 transform (no NaNs in this problem).
__device__ __forceinline__ unsigned fkey(float f) {
    unsigned b = __float_as_uint(f);
    return (b & 0x80000000u) ? ~b : (b | 0x80000000u);
}

// Per-lane candidate indices are strictly increasing, so strict > alone
// keeps the first max; the ==/idx< tie-break lives only in the reduces.
__device__ __forceinline__ void upd(float s, int idx, float& best, int& besti) {
    if (s > best) { best = s; besti = idx; }
}

__device__ __forceinline__ void body4(f32x4 l, unsigned w, int sh, float pen,
                                      int idx0, float& best, int& besti) {
    #pragma unroll
    for (int j = 0; j < 4; j++) {
        float present = (float)((w >> (sh + j)) & 1u);
        float p = l[j] - pen * present;           // exact: present in {0,1}
        upd(p, idx0 + j, best, besti);
    }
}

__device__ __forceinline__ void body4s(f32x4 l, f32x4 g, unsigned w, int sh,
                                       float pen, float temp,
                                       int idx0, float& best, int& besti) {
    #pragma unroll
    for (int j = 0; j < 4; j++) {
        float present = (float)((w >> (sh + j)) & 1u);
        float p = l[j] - pen * present;
        float s = p / temp + g[j];                // reference op order, IEEE div
        upd(s, idx0 + j, best, besti);
    }
}

// One block per row-eighth, 8 blocks/CU co-resident (launch_bounds pins
// VGPR<=64 so occupancy holds). Prologue: full-row presence mask in LDS
// (16 KB), two barriers total. Hot loop: wave-autonomous, 2-deep named
// prefetch (rule #20: no runtime-indexed arrays), nontemporal loads.
// Finalize: one atomicMax per wave; the 32nd wave of each row decodes and
// writes the output directly (no separate decode kernel).
__global__ __launch_bounds__(BBLOCK, 8) void fused_scan(
    const float* __restrict__ logits,        // [B, V]
    const float* __restrict__ gumbel,        // [B, V]
    const int*   __restrict__ token_ids,     // [B, L]
    const float* __restrict__ penalties,     // [B]
    const float* __restrict__ temps,         // [B]
    unsigned long long* __restrict__ keys,   // [B] packed (fkey(val)<<32)|~idx
    unsigned int* __restrict__ cnt,          // [B] finished-wave counters
    int* __restrict__ out)                   // [B]
{
    __shared__ unsigned smask[MASK_WORDS];   // 16 KB: full row mask

    const int blk  = blockIdx.x;
    const int row  = blk >> 3;               // 8 blocks per row
    const int tid  = threadIdx.x;
    const int lane = tid & 63;
    const int wave = tid >> 6;
    const int wir  = ((blk & 7) << 2) | wave;   // wave-in-row, 0..31

    const float pen    = penalties[row];
    const float temp   = temps[row];
    const bool  greedy = (temp < EPS_T);

    // ---- prologue: full-row presence mask (the only barriers in the kernel) ----
    const int4* rt = (const int4*)(token_ids + (size_t)row * HIST);
    int4 ta = rt[tid];
    int4 tb = rt[tid + BBLOCK];              // 2048 tokens = 512 int4

    for (int i = tid; i < MASK_WORDS; i += BBLOCK) smask[i] = 0u;
    __syncthreads();                          // zeros visible

    atomicOr(&smask[ta.x >> 5], 1u << (ta.x & 31));
    atomicOr(&smask[ta.y >> 5], 1u << (ta.y & 31));
    atomicOr(&smask[ta.z >> 5], 1u << (ta.z & 31));
    atomicOr(&smask[ta.w >> 5], 1u << (ta.w & 31));
    atomicOr(&smask[tb.x >> 5], 1u << (tb.x & 31));
    atomicOr(&smask[tb.y >> 5], 1u << (tb.y & 31));
    atomicOr(&smask[tb.z >> 5], 1u << (tb.z & 31));
    atomicOr(&smask[tb.w >> 5], 1u << (tb.w & 31));
    __syncthreads();                          // mask complete

    // ---- hot loop: wave-autonomous streaming, 2-deep prefetch ----
    const f32x4* Lr = (const f32x4*)(logits + (size_t)row * VOCAB);
    const f32x4* Gr = (const f32x4*)(gumbel + (size_t)row * VOCAB);

    float best  = -INFINITY;
    int   besti = 0x7fffffff;
    const int sh    = (lane & 7) * 4;         // bit shift within mask word
    const int wsub  = lane >> 3;              // word-in-chunk (8 words/chunk)

    if (greedy) {
        int c  = wir;
        int c1 = c + 32;
        f32x4 lc = __builtin_nontemporal_load(Lr + c * 64 + lane);
        f32x4 ln{};
        bool has1 = (c1 < CHUNKS);
        if (has1) ln = __builtin_nontemporal_load(Lr + c1 * 64 + lane);
        while (true) {
            const int c2 = c + 64;
            const bool has2 = (c2 < CHUNKS);
            f32x4 l2{};
            if (has2) l2 = __builtin_nontemporal_load(Lr + c2 * 64 + lane);
            const unsigned w = smask[c * 8 + wsub];
            body4(lc, w, sh, pen, c * 256 + lane * 4, best, besti);
            if (!has1) break;
            lc = ln; c = c1;
            ln = l2; c1 = c2; has1 = has2;
        }
    } else {
        int c  = wir;
        int c1 = c + 32;
        f32x4 lc = __builtin_nontemporal_load(Lr + c * 64 + lane);
        f32x4 gc = __builtin_nontemporal_load(Gr + c * 64 + lane);
        f32x4 ln{}, gn{};
        bool has1 = (c1 < CHUNKS);
        if (has1) {
            ln = __builtin_nontemporal_load(Lr + c1 * 64 + lane);
            gn = __builtin_nontemporal_load(Gr + c1 * 64 + lane);
        }
        while (true) {
            const int c2 = c + 64;
            const bool has2 = (c2 < CHUNKS);
            f32x4 l2{}, g2{};
            if (has2) {
                l2 = __builtin_nontemporal_load(Lr + c2 * 64 + lane);
                g2 = __builtin_nontemporal_load(Gr + c2 * 64 + lane);
            }
            const unsigned w = smask[c * 8 + wsub];
            body4s(lc, gc, w, sh, pen, temp, c * 256 + lane * 4, best, besti);
            if (!has1) break;
            lc = ln; gc = gn; c = c1;
            ln = l2; gn = g2; c1 = c2; has1 = has2;
        }
    }

    // wave argmax reduction (64 lanes), first-index tie-break
    #pragma unroll
    for (int off = 32; off > 0; off >>= 1) {
        float ov = __shfl_down(best, off, 64);
        int   oi = __shfl_down(besti, off, 64);
        if (ov > best || (ov == best && oi < besti)) { best = ov; besti = oi; }
    }

    // one device-scope atomic per wave; last wave of the row decodes + writes
    if (lane == 0) {
        unsigned long long key =
            ((unsigned long long)fkey(best) << 32) | (unsigned)(~besti);
        atomicMax(keys + row, key);
        __threadfence();                           // my max visible before count
        unsigned done = atomicAdd(cnt + row, 1u);
        if (done == WAVES_PER_ROW - 1) {
            // all 31 other maxes happened-before their counter bumps; this RMW
            // serializes after them at device scope -> returns the true max
            unsigned long long fin = atomicMax(keys + row, 0ull);
            out[row] = (int)(~(unsigned)fin);
        }
    }
}

extern "C" void kernel_launch(void* const* d_in, const int* in_sizes, int n_in,
                              void* d_out, int out_size, void* d_ws, size_t ws_size,
                              hipStream_t stream) {
    const float* logits    = (const float*)d_in[0];
    const int*   token_ids = (const int*)d_in[1];
    const float* penalties = (const float*)d_in[2];
    const float* temps     = (const float*)d_in[3];
    const float* gumbel    = (const float*)d_in[4];
    int* out = (int*)d_out;

    unsigned long long* keys = (unsigned long long*)d_ws;     // 2 KB
    unsigned int*       cnt  = (unsigned int*)(keys + BATCH); // 1 KB

    // keys = 0 is below every real packed key (fkey of any finite float > 0),
    // so memset-0 is a valid -inf init; cnt starts at 0. One contiguous memset.
    hipMemsetAsync(d_ws, 0,
                   BATCH * (sizeof(unsigned long long) + sizeof(unsigned int)),
                   stream);

    fused_scan<<<GRID, BBLOCK, 0, stream>>>(logits, gumbel, token_ids,
                                            penalties, temps, keys, cnt, out);
}

// Round 8
// 253.482 us; speedup vs baseline: 2.0867x; 2.0867x over previous
//
#include <hip/hip_runtime.h>
#include <math.h>

// Problem constants (match reference file).
#define BATCH 256
#define VOCAB 128000
#define HIST  2048
#define EPS_T 1e-5f

// --- barrier-free streaming scan ---
#define BBLOCK 256
#define BLOCKS_PER_ROW 8
#define GRID (BATCH * BLOCKS_PER_ROW)      // 2048 blocks = exactly 8/CU, co-resident
#define CHUNKS (VOCAB / 256)               // 500 chunks of 256 elems per row
#define MASK_WORDS (VOCAB / 32)            // 4000 words = 16 KB full-row mask
// contiguous chunk runs per wave: 500 = 20 waves * 16 + 12 waves * 15
#define BASE_CH (CHUNKS / 32)              // 15
#define EXTRA_W (CHUNKS - 32 * BASE_CH)    // 20

typedef float f32x4 __attribute__((ext_vector_type(4)));

// Order-preserving f32 -> u32 transform (no NaNs in this problem).
__device__ __forceinline__ unsigned fkey(float f) {
    unsigned b = __float_as_uint(f);
    return (b & 0x80000000u) ? ~b : (b | 0x80000000u);
}

// Per-lane candidate indices are strictly increasing (chunk index grows,
// j grows), so strict > alone keeps the first max; the ==/idx< tie-break
// lives only in the cross-lane / cross-wave reduces.
__device__ __forceinline__ void upd(float s, int idx, float& best, int& besti) {
    if (s > best) { best = s; besti = idx; }
}

__device__ __forceinline__ void body4(f32x4 l, unsigned w, int sh, float pen,
                                      int idx0, float& best, int& besti) {
    #pragma unroll
    for (int j = 0; j < 4; j++) {
        float present = (float)((w >> (sh + j)) & 1u);
        float p = l[j] - pen * present;           // exact: present in {0,1}
        upd(p, idx0 + j, best, besti);
    }
}

__device__ __forceinline__ void body4s(f32x4 l, f32x4 g, unsigned w, int sh,
                                       float pen, float temp,
                                       int idx0, float& best, int& besti) {
    #pragma unroll
    for (int j = 0; j < 4; j++) {
        float present = (float)((w >> (sh + j)) & 1u);
        float p = l[j] - pen * present;
        float s = p / temp + g[j];                // reference op order, IEEE div
        upd(s, idx0 + j, best, besti);
    }
}

// One block per row-eighth, co-resident grid. Prologue: full-row presence
// mask in LDS (16 KB), two barriers total. Hot loop: wave-autonomous over a
// CONTIGUOUS run of 15-16 chunks, rotated 1-deep prefetch with an
// UNCONDITIONAL body (no branch between issue and consume -> compiler can
// emit precise vmcnt(2) instead of a conservative drain). Nontemporal loads
// for the zero-reuse streams. One atomicMax per wave; tiny decode kernel.
__global__ __launch_bounds__(BBLOCK, 1) void fused_scan(
    const float* __restrict__ logits,        // [B, V]
    const float* __restrict__ gumbel,        // [B, V]
    const int*   __restrict__ token_ids,     // [B, L]
    const float* __restrict__ penalties,     // [B]
    const float* __restrict__ temps,         // [B]
    unsigned long long* __restrict__ keys)   // [B] packed (fkey(val)<<32)|~idx
{
    __shared__ unsigned smask[MASK_WORDS];   // 16 KB: full row mask

    const int blk  = blockIdx.x;
    const int row  = blk >> 3;               // 8 blocks per row
    const int tid  = threadIdx.x;
    const int lane = tid & 63;
    const int wave = tid >> 6;
    const int wir  = ((blk & 7) << 2) | wave;   // wave-in-row, 0..31

    const float pen    = penalties[row];
    const float temp   = temps[row];
    const bool  greedy = (temp < EPS_T);

    // ---- prologue: full-row presence mask (the only barriers in the kernel) ----
    const int4* rt = (const int4*)(token_ids + (size_t)row * HIST);
    int4 ta = rt[tid];
    int4 tb = rt[tid + BBLOCK];              // 2048 tokens = 512 int4

    for (int i = tid; i < MASK_WORDS; i += BBLOCK) smask[i] = 0u;
    __syncthreads();                          // zeros visible

    atomicOr(&smask[ta.x >> 5], 1u << (ta.x & 31));
    atomicOr(&smask[ta.y >> 5], 1u << (ta.y & 31));
    atomicOr(&smask[ta.z >> 5], 1u << (ta.z & 31));
    atomicOr(&smask[ta.w >> 5], 1u << (ta.w & 31));
    atomicOr(&smask[tb.x >> 5], 1u << (tb.x & 31));
    atomicOr(&smask[tb.y >> 5], 1u << (tb.y & 31));
    atomicOr(&smask[tb.z >> 5], 1u << (tb.z & 31));
    atomicOr(&smask[tb.w >> 5], 1u << (tb.w & 31));
    __syncthreads();                          // mask complete

    // ---- hot loop: wave-autonomous streaming over contiguous chunks ----
    const f32x4* Lr = (const f32x4*)(logits + (size_t)row * VOCAB);
    const f32x4* Gr = (const f32x4*)(gumbel + (size_t)row * VOCAB);

    float best  = -INFINITY;
    int   besti = 0x7fffffff;
    const int sh    = (lane & 7) * 4;         // bit shift within mask word
    const int wsub  = lane >> 3;              // word-in-chunk (8 words/chunk)

    const int n  = BASE_CH + (wir < EXTRA_W ? 1 : 0);               // 15 or 16
    const int c0 = wir * BASE_CH + (wir < EXTRA_W ? wir : EXTRA_W); // run start

    if (greedy) {
        int c = c0;
        f32x4 lc = __builtin_nontemporal_load(Lr + (size_t)c * 64 + lane);
        for (int i = 1; i < n; ++i) {
            f32x4 ln = __builtin_nontemporal_load(Lr + (size_t)(c0 + i) * 64 + lane);
            const unsigned w = smask[c * 8 + wsub];
            body4(lc, w, sh, pen, c * 256 + lane * 4, best, besti);
            lc = ln; c = c0 + i;
        }
        const unsigned w = smask[c * 8 + wsub];
        body4(lc, w, sh, pen, c * 256 + lane * 4, best, besti);
    } else {
        int c = c0;
        f32x4 lc = __builtin_nontemporal_load(Lr + (size_t)c * 64 + lane);
        f32x4 gc = __builtin_nontemporal_load(Gr + (size_t)c * 64 + lane);
        for (int i = 1; i < n; ++i) {
            f32x4 ln = __builtin_nontemporal_load(Lr + (size_t)(c0 + i) * 64 + lane);
            f32x4 gn = __builtin_nontemporal_load(Gr + (size_t)(c0 + i) * 64 + lane);
            const unsigned w = smask[c * 8 + wsub];
            body4s(lc, gc, w, sh, pen, temp, c * 256 + lane * 4, best, besti);
            lc = ln; gc = gn; c = c0 + i;
        }
        const unsigned w = smask[c * 8 + wsub];
        body4s(lc, gc, w, sh, pen, temp, c * 256 + lane * 4, best, besti);
    }

    // wave argmax reduction (64 lanes), first-index tie-break
    #pragma unroll
    for (int off = 32; off > 0; off >>= 1) {
        float ov = __shfl_down(best, off, 64);
        int   oi = __shfl_down(besti, off, 64);
        if (ov > best || (ov == best && oi < besti)) { best = ov; besti = oi; }
    }

    // one device-scope atomic per wave (32 per row total)
    if (lane == 0) {
        unsigned long long key =
            ((unsigned long long)fkey(best) << 32) | (unsigned)(~besti);
        atomicMax(keys + row, key);
    }
}

__global__ void decode_kernel(const unsigned long long* __restrict__ keys,
                              int* __restrict__ out)
{
    const int b = threadIdx.x;                 // 256 threads, one per row
    out[b] = (int)(~(unsigned)keys[b]);
}

extern "C" void kernel_launch(void* const* d_in, const int* in_sizes, int n_in,
                              void* d_out, int out_size, void* d_ws, size_t ws_size,
                              hipStream_t stream) {
    const float* logits    = (const float*)d_in[0];
    const int*   token_ids = (const int*)d_in[1];
    const float* penalties = (const float*)d_in[2];
    const float* temps     = (const float*)d_in[3];
    const float* gumbel    = (const float*)d_in[4];
    int* out = (int*)d_out;

    unsigned long long* keys = (unsigned long long*)d_ws;   // 2 KB

    // keys = 0 is below every real packed key (fkey of any finite float > 0),
    // so memset-0 is a valid -inf init.
    hipMemsetAsync(keys, 0, BATCH * sizeof(unsigned long long), stream);

    fused_scan<<<GRID, BBLOCK, 0, stream>>>(logits, gumbel, token_ids,
                                            penalties, temps, keys);
    decode_kernel<<<1, BATCH, 0, stream>>>(keys, out);
}